// Round 1
// baseline (652.891 us; speedup 1.0000x reference)
//
#include <hip/hip_runtime.h>

typedef _Float16 half8 __attribute__((ext_vector_type(8)));
typedef _Float16 half4 __attribute__((ext_vector_type(4)));
typedef float    floatx4 __attribute__((ext_vector_type(4)));
typedef int      intx4  __attribute__((ext_vector_type(4)));

#define NB  16
#define SEQ 2048
#define DIM 64

#define MFMA(a,b,c) __builtin_amdgcn_mfma_f32_16x16x32_f16((a),(b),(c),0,0,0)

// ---- pre-pass: q,k fp32 -> f16 (straight copy-convert) ----
__global__ __launch_bounds__(256) void cvt_qk_kernel(const float* __restrict__ q,
                                                     const float* __restrict__ k,
                                                     _Float16* __restrict__ qh,
                                                     _Float16* __restrict__ kh) {
    size_t i = ((size_t)blockIdx.x * 256 + threadIdx.x) * 4;
    float4 a = *(const float4*)(q + i);
    float4 b = *(const float4*)(k + i);
    half4 ha = { (_Float16)a.x, (_Float16)a.y, (_Float16)a.z, (_Float16)a.w };
    half4 hb = { (_Float16)b.x, (_Float16)b.y, (_Float16)b.z, (_Float16)b.w };
    *(half4*)(qh + i) = ha;
    *(half4*)(kh + i) = hb;
}

// ---- pre-pass: v [B][S][D] fp32 -> vt [B][D][S] f16 (LDS tile transpose) ----
__global__ __launch_bounds__(256) void cvt_vt_kernel(const float* __restrict__ v,
                                                     _Float16* __restrict__ vt) {
    __shared__ float tile[64][65];
    const int b  = blockIdx.x >> 5;
    const int s0 = (blockIdx.x & 31) << 6;
    const int t  = threadIdx.x;
    {
        const int row = t >> 2;            // s-local 0..63
        const int c0  = (t & 3) << 4;      // d base
        const float* src = v + ((size_t)(b * SEQ + s0 + row)) * DIM + c0;
        #pragma unroll
        for (int i = 0; i < 4; ++i) {
            float4 x = *(const float4*)(src + i * 4);
            tile[row][c0 + i*4 + 0] = x.x;
            tile[row][c0 + i*4 + 1] = x.y;
            tile[row][c0 + i*4 + 2] = x.z;
            tile[row][c0 + i*4 + 3] = x.w;
        }
    }
    __syncthreads();
    {
        const int d  = t >> 2;             // 0..63
        const int sb = (t & 3) << 4;       // s-local base
        _Float16* dst = vt + ((size_t)(b * DIM + d)) * SEQ + s0 + sb;
        #pragma unroll
        for (int i = 0; i < 4; ++i) {
            half4 h = { (_Float16)tile[sb + i*4 + 0][d],
                        (_Float16)tile[sb + i*4 + 1][d],
                        (_Float16)tile[sb + i*4 + 2][d],
                        (_Float16)tile[sb + i*4 + 3][d] };
            *(half4*)(dst + i*4) = h;
        }
    }
}

// ---- fused attention: one block = 16 q-rows of one b ----
// Two passes over columns, NO full-row e buffer (recompute QK in pass B).
// Swapped QK^T: c = mfma(A=K, B=Q) => lane(rl,g) reg i holds
//   s[q-row rl][key col j0 + (tile16)*16 + g*4 + i]  -- q-row is lane-local.
// Pass A: rowsum of exp + mask bits packed into a 128-bit register shift-queue.
// Pass B: recompute, write normalized fp32 attn straight from registers,
//   bounce e(f16) through a 1.25KB per-wave LDS tile into the PV B-fragment,
//   accumulate this wave's column-partial of out[16][64]; cross-wave LDS reduce.
__global__ __launch_bounds__(256, 4) void attn_kernel(
    const _Float16* __restrict__ qh, const _Float16* __restrict__ kh,
    const _Float16* __restrict__ vt, const int* __restrict__ mask,
    float* __restrict__ out, float* __restrict__ attn)
{
    __shared__ float wsum[4][16];
    __shared__ __align__(16) _Float16 tsc[4][16][40];   // per-wave transpose scratch (row pad 40)
    __shared__ __align__(16) float outred[4][16][68];   // cross-wave out reduction (row pad 68)

    const int b    = blockIdx.x >> 7;
    const int r0   = (blockIdx.x & 127) << 4;
    const int lane = threadIdx.x & 63;
    const int wave = threadIdx.x >> 6;
    const int rl   = lane & 15;   // q-row (MFMA n-index)
    const int g    = lane >> 4;   // quad

    // Q fragment (B-operand of swapped QK): Q[r0+rl][g*8..+7], both K=32 halves
    const size_t qoff = ((size_t)(b * SEQ + r0 + rl)) * DIM + g * 8;
    const half8 qa0 = *(const half8*)(qh + qoff);
    const half8 qa1 = *(const half8*)(qh + qoff + 32);

    const _Float16* kbase = kh + (size_t)b * SEQ * DIM + (size_t)rl * DIM + g * 8;
    const int*      mbase = mask + ((size_t)(b * SEQ + r0 + rl)) * SEQ + g * 4;

    // ---------------- pass A: row sums + mask-bit capture ----------------
    float rs = 0.f;
    uint32_t mb0 = 0, mb1 = 0, mb2 = 0, mb3 = 0;   // 128-bit shift queue, static idx

    intx4 pm0 = __builtin_nontemporal_load((const intx4*)(mbase + wave * 32));
    intx4 pm1 = __builtin_nontemporal_load((const intx4*)(mbase + wave * 32 + 16));

    for (int cc = 0; cc < 16; ++cc) {
        const int jj = (cc * 4 + wave) * 32;       // this wave's 32-col chunk
        const intx4 m0 = pm0, m1 = pm1;
        if (cc < 15) {                              // prefetch next chunk's mask
            pm0 = __builtin_nontemporal_load((const intx4*)(mbase + jj + 128));
            pm1 = __builtin_nontemporal_load((const intx4*)(mbase + jj + 128 + 16));
        }
        const _Float16* kp = kbase + (size_t)jj * DIM;
        half8 ka0 = *(const half8*)(kp);
        half8 ka1 = *(const half8*)(kp + 32);
        half8 kb0 = *(const half8*)(kp + 16 * DIM);
        half8 kb1 = *(const half8*)(kp + 16 * DIM + 32);
        floatx4 c0 = {0.f,0.f,0.f,0.f}, c1 = {0.f,0.f,0.f,0.f};
        c0 = MFMA(ka0, qa0, c0);
        c0 = MFMA(ka1, qa1, c0);
        c1 = MFMA(kb0, qa0, c1);
        c1 = MFMA(kb1, qa1, c1);
        // c0[i] = s[rl][jj+g*4+i], c1[i] = s[rl][jj+16+g*4+i]
        float e0 = m0.x ? 0.f : __expf(c0[0] * 0.125f);
        float e1 = m0.y ? 0.f : __expf(c0[1] * 0.125f);
        float e2 = m0.z ? 0.f : __expf(c0[2] * 0.125f);
        float e3 = m0.w ? 0.f : __expf(c0[3] * 0.125f);
        float e4 = m1.x ? 0.f : __expf(c1[0] * 0.125f);
        float e5 = m1.y ? 0.f : __expf(c1[1] * 0.125f);
        float e6 = m1.z ? 0.f : __expf(c1[2] * 0.125f);
        float e7 = m1.w ? 0.f : __expf(c1[3] * 0.125f);
        rs += (e0 + e1) + (e2 + e3) + (e4 + e5) + (e6 + e7);
        uint32_t byt = (m0.x ? 1u : 0u)        | ((m0.y ? 1u : 0u) << 1)
                     | ((m0.z ? 1u : 0u) << 2) | ((m0.w ? 1u : 0u) << 3)
                     | ((m1.x ? 1u : 0u) << 4) | ((m1.y ? 1u : 0u) << 5)
                     | ((m1.z ? 1u : 0u) << 6) | ((m1.w ? 1u : 0u) << 7);
        mb0 = (mb0 >> 8) | (mb1 << 24);
        mb1 = (mb1 >> 8) | (mb2 << 24);
        mb2 = (mb2 >> 8) | (mb3 << 24);
        mb3 = (mb3 >> 8) | (byt << 24);
    }

    // row-sum: the 4 lanes sharing rl are {l, l^16, l^32, l^48}
    rs += __shfl_xor(rs, 16);
    rs += __shfl_xor(rs, 32);
    if (g == 0) wsum[wave][rl] = rs;
    __syncthreads();
    const float inv = 1.0f / (wsum[0][rl] + wsum[1][rl] + wsum[2][rl] + wsum[3][rl]);

    // ---------------- pass B: recompute, emit attn, accumulate PV ----------------
    floatx4 o0 = {0.f,0.f,0.f,0.f}, o1 = {0.f,0.f,0.f,0.f};
    floatx4 o2 = {0.f,0.f,0.f,0.f}, o3 = {0.f,0.f,0.f,0.f};
    const _Float16* vbase = vt + ((size_t)b * DIM + rl) * SEQ + g * 8;
    float* abase = attn + ((size_t)(b * SEQ + r0 + rl)) * SEQ + g * 4;

    for (int cc = 0; cc < 16; ++cc) {
        const int jj = (cc * 4 + wave) * 32;
        const _Float16* kp = kbase + (size_t)jj * DIM;
        half8 ka0 = *(const half8*)(kp);
        half8 ka1 = *(const half8*)(kp + 32);
        half8 kb0 = *(const half8*)(kp + 16 * DIM);
        half8 kb1 = *(const half8*)(kp + 16 * DIM + 32);
        floatx4 c0 = {0.f,0.f,0.f,0.f}, c1 = {0.f,0.f,0.f,0.f};
        c0 = MFMA(ka0, qa0, c0);
        c0 = MFMA(ka1, qa1, c0);
        c1 = MFMA(kb0, qa0, c1);
        c1 = MFMA(kb1, qa1, c1);

        const uint32_t byt = mb0 & 0xffu;
        mb0 = (mb0 >> 8) | (mb1 << 24);
        mb1 = (mb1 >> 8) | (mb2 << 24);
        mb2 = (mb2 >> 8) | (mb3 << 24);
        mb3 =  mb3 >> 8;

        float e0 = (byt & 1u)   ? 0.f : __expf(c0[0] * 0.125f);
        float e1 = (byt & 2u)   ? 0.f : __expf(c0[1] * 0.125f);
        float e2 = (byt & 4u)   ? 0.f : __expf(c0[2] * 0.125f);
        float e3 = (byt & 8u)   ? 0.f : __expf(c0[3] * 0.125f);
        float e4 = (byt & 16u)  ? 0.f : __expf(c1[0] * 0.125f);
        float e5 = (byt & 32u)  ? 0.f : __expf(c1[1] * 0.125f);
        float e6 = (byt & 64u)  ? 0.f : __expf(c1[2] * 0.125f);
        float e7 = (byt & 128u) ? 0.f : __expf(c1[3] * 0.125f);

        // attn: normalized fp32, straight from registers (cols jj+g*4.., jj+16+g*4..)
        floatx4 a0 = { e0 * inv, e1 * inv, e2 * inv, e3 * inv };
        floatx4 a1 = { e4 * inv, e5 * inv, e6 * inv, e7 * inv };
        __builtin_nontemporal_store(a0, (floatx4*)(abase + jj));
        __builtin_nontemporal_store(a1, (floatx4*)(abase + jj + 16));

        // e -> f16, per-wave LDS bounce into PV B-fragment layout
        half4 h0 = { (_Float16)e0, (_Float16)e1, (_Float16)e2, (_Float16)e3 };
        half4 h1 = { (_Float16)e4, (_Float16)e5, (_Float16)e6, (_Float16)e7 };
        *(half4*)(&tsc[wave][rl][g * 4])      = h0;
        *(half4*)(&tsc[wave][rl][16 + g * 4]) = h1;
        half8 eb = *(const half8*)(&tsc[wave][rl][g * 8]);   // e[rl][jj+g*8..+7]

        // PV: out^T[d][rl] += V^T[d][j] * e^T[j][rl], d tiled by 16
        const _Float16* vp = vbase + jj;
        half8 v0 = *(const half8*)(vp);
        half8 v1 = *(const half8*)(vp + 16 * SEQ);
        half8 v2 = *(const half8*)(vp + 32 * SEQ);
        half8 v3 = *(const half8*)(vp + 48 * SEQ);
        o0 = MFMA(v0, eb, o0);
        o1 = MFMA(v1, eb, o1);
        o2 = MFMA(v2, eb, o2);
        o3 = MFMA(v3, eb, o3);
    }

    // ---- cross-wave reduction of out partials ----
    // o{dt}[i] = out[rl][dt*16 + g*4 + i] (this wave's columns only, unnormalized)
    *(floatx4*)(&outred[wave][rl][ 0 + g * 4]) = o0;
    *(floatx4*)(&outred[wave][rl][16 + g * 4]) = o1;
    *(floatx4*)(&outred[wave][rl][32 + g * 4]) = o2;
    *(floatx4*)(&outred[wave][rl][48 + g * 4]) = o3;
    __syncthreads();
    {
        const int r  = threadIdx.x >> 4;        // 0..15
        const int c4 = (threadIdx.x & 15) << 2; // 0,4,..,60
        floatx4 s0 = *(const floatx4*)(&outred[0][r][c4]);
        floatx4 s1 = *(const floatx4*)(&outred[1][r][c4]);
        floatx4 s2 = *(const floatx4*)(&outred[2][r][c4]);
        floatx4 s3 = *(const floatx4*)(&outred[3][r][c4]);
        floatx4 s = (s0 + s1) + (s2 + s3);
        const float inv2 = 1.0f / (wsum[0][r] + wsum[1][r] + wsum[2][r] + wsum[3][r]);
        floatx4 ov = { s[0] * inv2, s[1] * inv2, s[2] * inv2, s[3] * inv2 };
        *(floatx4*)(out + ((size_t)(b * SEQ + r0 + r)) * DIM + c4) = ov;
    }
}

extern "C" void kernel_launch(void* const* d_in, const int* in_sizes, int n_in,
                              void* d_out, int out_size, void* d_ws, size_t ws_size,
                              hipStream_t stream) {
    const float* q = (const float*)d_in[0];
    const float* k = (const float*)d_in[1];
    const float* v = (const float*)d_in[2];
    const int* mask = (const int*)d_in[3];   // bool delivered as int32 per harness

    float* out  = (float*)d_out;                       // [16,2048,64]
    float* attn = out + (size_t)NB * SEQ * DIM;        // [16,2048,2048]

    // workspace: qh | kh | vt  (f16, 4 MB each = 12 MB total)
    _Float16* qh = (_Float16*)d_ws;
    _Float16* kh = qh + (size_t)NB * SEQ * DIM;
    _Float16* vt = kh + (size_t)NB * SEQ * DIM;

    cvt_qk_kernel<<<(NB * SEQ * DIM) / 1024, 256, 0, stream>>>(q, k, qh, kh);
    cvt_vt_kernel<<<NB * (SEQ / 64), 256, 0, stream>>>(v, vt);
    attn_kernel<<<NB * (SEQ / 16), 256, 0, stream>>>(qh, kh, vt, mask, out, attn);
}

// Round 2
// 623.754 us; speedup vs baseline: 1.0467x; 1.0467x over previous
//
#include <hip/hip_runtime.h>

typedef _Float16 half8 __attribute__((ext_vector_type(8)));
typedef _Float16 half4 __attribute__((ext_vector_type(4)));
typedef float    floatx4 __attribute__((ext_vector_type(4)));

#define NB  16
#define SEQ 2048
#define DIM 64

#define MFMA(a,b,c) __builtin_amdgcn_mfma_f32_16x16x32_f16((a),(b),(c),0,0,0)

// ---- pre-pass: q,k fp32 -> f16 (straight copy-convert) ----
__global__ __launch_bounds__(256) void cvt_qk_kernel(const float* __restrict__ q,
                                                     const float* __restrict__ k,
                                                     _Float16* __restrict__ qh,
                                                     _Float16* __restrict__ kh) {
    size_t i = ((size_t)blockIdx.x * 256 + threadIdx.x) * 4;
    float4 a = *(const float4*)(q + i);
    float4 b = *(const float4*)(k + i);
    half4 ha = { (_Float16)a.x, (_Float16)a.y, (_Float16)a.z, (_Float16)a.w };
    half4 hb = { (_Float16)b.x, (_Float16)b.y, (_Float16)b.z, (_Float16)b.w };
    *(half4*)(qh + i) = ha;
    *(half4*)(kh + i) = hb;
}

// ---- pre-pass: v [B][S][D] fp32 -> vt [B][D][S] f16 (LDS tile transpose) ----
__global__ __launch_bounds__(256) void cvt_vt_kernel(const float* __restrict__ v,
                                                     _Float16* __restrict__ vt) {
    __shared__ float tile[64][65];
    const int b  = blockIdx.x >> 5;
    const int s0 = (blockIdx.x & 31) << 6;
    const int t  = threadIdx.x;
    {
        const int row = t >> 2;            // s-local 0..63
        const int c0  = (t & 3) << 4;      // d base
        const float* src = v + ((size_t)(b * SEQ + s0 + row)) * DIM + c0;
        #pragma unroll
        for (int i = 0; i < 4; ++i) {
            float4 x = *(const float4*)(src + i * 4);
            tile[row][c0 + i*4 + 0] = x.x;
            tile[row][c0 + i*4 + 1] = x.y;
            tile[row][c0 + i*4 + 2] = x.z;
            tile[row][c0 + i*4 + 3] = x.w;
        }
    }
    __syncthreads();
    {
        const int d  = t >> 2;             // 0..63
        const int sb = (t & 3) << 4;       // s-local base
        _Float16* dst = vt + ((size_t)(b * DIM + d)) * SEQ + s0 + sb;
        #pragma unroll
        for (int i = 0; i < 4; ++i) {
            half4 h = { (_Float16)tile[sb + i*4 + 0][d],
                        (_Float16)tile[sb + i*4 + 1][d],
                        (_Float16)tile[sb + i*4 + 2][d],
                        (_Float16)tile[sb + i*4 + 3][d] };
            *(half4*)(dst + i*4) = h;
        }
    }
}

// ---- pre-pass: mask int32 -> 1 bit/elem via ballot ----
// bits[row][w] (w=0..63): bit t of dword w = mask[row][w*32+t] != 0.
// One wave per row; iteration it ballots cols [it*64, it*64+64); lanes 2it/2it+1
// keep the lo/hi halves; final store is one fully-coalesced dword per lane.
__global__ __launch_bounds__(256) void mask_bits_kernel(const int* __restrict__ mask,
                                                        unsigned int* __restrict__ bits) {
    const int wave = threadIdx.x >> 6;
    const int lane = threadIdx.x & 63;
    const size_t row = (size_t)blockIdx.x * 4 + wave;   // 16*2048 rows total
    const int* mp = mask + row * SEQ + lane;
    unsigned int keep = 0;
    #pragma unroll
    for (int it = 0; it < 32; ++it) {
        int m = __builtin_nontemporal_load(mp + it * 64);
        unsigned long long bal = __ballot(m != 0);
        unsigned int half = (lane & 1) ? (unsigned int)(bal >> 32) : (unsigned int)bal;
        if ((lane >> 1) == it) keep = half;
    }
    bits[row * 64 + lane] = keep;
}

// ---- fused attention: one block = 16 q-rows of one b ----
// Two passes over columns, NO full-row e buffer (recompute QK in pass B).
// Swapped QK^T: c = mfma(A=K, B=Q) => lane(rl,g) reg i holds
//   s[q-row rl][key col jj + g*4+i] (c0) and jj+16+g*4+i (c1).
// Mask comes as a 1-bit stream (4 B/lane/iter, L2-resident).
// Pass A: rowsum of exp. Pass B: recompute, write normalized fp32 attn straight
// from registers (plain stores -> L2 merges half-lines), bounce e(f16) through a
// per-wave LDS tile into the PV B-fragment, accumulate column-partials of
// out[16][64]; cross-wave LDS reduce. tsc/outred share one LDS region (barrier
// separates last tsc use from first outred write) -> 17.7 KB LDS, 8 blocks/CU.
__global__ __launch_bounds__(256, 8) void attn_kernel(
    const _Float16* __restrict__ qh, const _Float16* __restrict__ kh,
    const _Float16* __restrict__ vt, const unsigned int* __restrict__ bits,
    float* __restrict__ out, float* __restrict__ attn)
{
    __shared__ float wsum[4][16];
    __shared__ __align__(16) unsigned char lds_u[4 * 16 * 68 * 4];  // 17408 B, aliased
    _Float16* tsc    = (_Float16*)lds_u;   // [4][16][40] halves (row pad 40)
    float*    outred = (float*)lds_u;      // [4][16][68] floats (row pad 68)

    const int b    = blockIdx.x >> 7;
    const int r0   = (blockIdx.x & 127) << 4;
    const int lane = threadIdx.x & 63;
    const int wave = threadIdx.x >> 6;
    const int rl   = lane & 15;   // q-row (MFMA n-index)
    const int g    = lane >> 4;   // quad

    // Q fragment (B-operand of swapped QK): Q[r0+rl][g*8..+7], both K=32 halves
    const size_t qoff = ((size_t)(b * SEQ + r0 + rl)) * DIM + g * 8;
    const half8 qa0 = *(const half8*)(qh + qoff);
    const half8 qa1 = *(const half8*)(qh + qoff + 32);

    const _Float16* kbase = kh + (size_t)b * SEQ * DIM + (size_t)rl * DIM + g * 8;
    const unsigned int* bbase = bits + ((size_t)(b * SEQ + r0 + rl)) * 64 + wave;

    // ---------------- pass A: row sums ----------------
    float rs = 0.f;
    unsigned int pb = bbase[0];

    for (int cc = 0; cc < 16; ++cc) {
        const int jj = (cc * 4 + wave) * 32;       // this wave's 32-col chunk
        const unsigned int bm = pb;
        if (cc < 15) pb = bbase[(cc + 1) * 4];     // prefetch next chunk's bits
        const _Float16* kp = kbase + (size_t)jj * DIM;
        half8 ka0 = *(const half8*)(kp);
        half8 ka1 = *(const half8*)(kp + 32);
        half8 kb0 = *(const half8*)(kp + 16 * DIM);
        half8 kb1 = *(const half8*)(kp + 16 * DIM + 32);
        floatx4 c0 = {0.f,0.f,0.f,0.f}, c1 = {0.f,0.f,0.f,0.f};
        c0 = MFMA(ka0, qa0, c0);
        c0 = MFMA(ka1, qa1, c0);
        c1 = MFMA(kb0, qa0, c1);
        c1 = MFMA(kb1, qa1, c1);
        const unsigned int blo = bm >> (g * 4);
        const unsigned int bhi = bm >> (g * 4 + 16);
        float e0 = (blo & 1u) ? 0.f : __expf(c0[0] * 0.125f);
        float e1 = (blo & 2u) ? 0.f : __expf(c0[1] * 0.125f);
        float e2 = (blo & 4u) ? 0.f : __expf(c0[2] * 0.125f);
        float e3 = (blo & 8u) ? 0.f : __expf(c0[3] * 0.125f);
        float e4 = (bhi & 1u) ? 0.f : __expf(c1[0] * 0.125f);
        float e5 = (bhi & 2u) ? 0.f : __expf(c1[1] * 0.125f);
        float e6 = (bhi & 4u) ? 0.f : __expf(c1[2] * 0.125f);
        float e7 = (bhi & 8u) ? 0.f : __expf(c1[3] * 0.125f);
        rs += (e0 + e1) + (e2 + e3) + (e4 + e5) + (e6 + e7);
    }

    // row-sum: the 4 lanes sharing rl are {l, l^16, l^32, l^48}
    rs += __shfl_xor(rs, 16);
    rs += __shfl_xor(rs, 32);
    if (g == 0) wsum[wave][rl] = rs;
    __syncthreads();
    const float inv = 1.0f / (wsum[0][rl] + wsum[1][rl] + wsum[2][rl] + wsum[3][rl]);

    // ---------------- pass B: recompute, emit attn, accumulate PV ----------------
    floatx4 o0 = {0.f,0.f,0.f,0.f}, o1 = {0.f,0.f,0.f,0.f};
    floatx4 o2 = {0.f,0.f,0.f,0.f}, o3 = {0.f,0.f,0.f,0.f};
    const _Float16* vbase = vt + ((size_t)b * DIM + rl) * SEQ + g * 8;
    float* abase = attn + ((size_t)(b * SEQ + r0 + rl)) * SEQ + g * 4;
    _Float16* trow = tsc + (wave * 16 + rl) * 40;

    for (int cc = 0; cc < 16; ++cc) {
        const int jj = (cc * 4 + wave) * 32;
        const unsigned int bm = bbase[cc * 4];     // L1/L2-hot after pass A
        const _Float16* kp = kbase + (size_t)jj * DIM;
        half8 ka0 = *(const half8*)(kp);
        half8 ka1 = *(const half8*)(kp + 32);
        half8 kb0 = *(const half8*)(kp + 16 * DIM);
        half8 kb1 = *(const half8*)(kp + 16 * DIM + 32);
        floatx4 c0 = {0.f,0.f,0.f,0.f}, c1 = {0.f,0.f,0.f,0.f};
        c0 = MFMA(ka0, qa0, c0);
        c0 = MFMA(ka1, qa1, c0);
        c1 = MFMA(kb0, qa0, c1);
        c1 = MFMA(kb1, qa1, c1);

        const unsigned int blo = bm >> (g * 4);
        const unsigned int bhi = bm >> (g * 4 + 16);
        float e0 = (blo & 1u) ? 0.f : __expf(c0[0] * 0.125f);
        float e1 = (blo & 2u) ? 0.f : __expf(c0[1] * 0.125f);
        float e2 = (blo & 4u) ? 0.f : __expf(c0[2] * 0.125f);
        float e3 = (blo & 8u) ? 0.f : __expf(c0[3] * 0.125f);
        float e4 = (bhi & 1u) ? 0.f : __expf(c1[0] * 0.125f);
        float e5 = (bhi & 2u) ? 0.f : __expf(c1[1] * 0.125f);
        float e6 = (bhi & 4u) ? 0.f : __expf(c1[2] * 0.125f);
        float e7 = (bhi & 8u) ? 0.f : __expf(c1[3] * 0.125f);

        // attn: normalized fp32, straight from registers; plain stores so the
        // two 64B half-lines of each 128B line merge in L2 before writeback
        floatx4 a0 = { e0 * inv, e1 * inv, e2 * inv, e3 * inv };
        floatx4 a1 = { e4 * inv, e5 * inv, e6 * inv, e7 * inv };
        *(floatx4*)(abase + jj)      = a0;
        *(floatx4*)(abase + jj + 16) = a1;

        // e -> f16, per-wave LDS bounce into PV B-fragment layout
        half4 h0 = { (_Float16)e0, (_Float16)e1, (_Float16)e2, (_Float16)e3 };
        half4 h1 = { (_Float16)e4, (_Float16)e5, (_Float16)e6, (_Float16)e7 };
        *(half4*)(trow + g * 4)      = h0;
        *(half4*)(trow + 16 + g * 4) = h1;
        half8 eb = *(const half8*)(trow + g * 8);   // e[rl][jj+g*8..+7]

        // PV: out^T[d][rl] += V^T[d][j] * e^T[j][rl], d tiled by 16
        const _Float16* vp = vbase + jj;
        half8 v0 = *(const half8*)(vp);
        half8 v1 = *(const half8*)(vp + 16 * SEQ);
        half8 v2 = *(const half8*)(vp + 32 * SEQ);
        half8 v3 = *(const half8*)(vp + 48 * SEQ);
        o0 = MFMA(v0, eb, o0);
        o1 = MFMA(v1, eb, o1);
        o2 = MFMA(v2, eb, o2);
        o3 = MFMA(v3, eb, o3);
    }

    // ---- cross-wave reduction of out partials ----
    // outred aliases tsc: all waves must be done with tsc before first write.
    __syncthreads();
    {
        float* orow = outred + (wave * 16 + rl) * 68 + g * 4;
        *(floatx4*)(orow +  0) = o0;
        *(floatx4*)(orow + 16) = o1;
        *(floatx4*)(orow + 32) = o2;
        *(floatx4*)(orow + 48) = o3;
    }
    __syncthreads();
    {
        const int r  = threadIdx.x >> 4;        // 0..15
        const int c4 = (threadIdx.x & 15) << 2; // 0,4,..,60
        floatx4 s0 = *(const floatx4*)(outred + ( 0 + r) * 68 + c4);
        floatx4 s1 = *(const floatx4*)(outred + (16 + r) * 68 + c4);
        floatx4 s2 = *(const floatx4*)(outred + (32 + r) * 68 + c4);
        floatx4 s3 = *(const floatx4*)(outred + (48 + r) * 68 + c4);
        floatx4 s = (s0 + s1) + (s2 + s3);
        const float inv2 = 1.0f / (wsum[0][r] + wsum[1][r] + wsum[2][r] + wsum[3][r]);
        floatx4 ov = { s[0] * inv2, s[1] * inv2, s[2] * inv2, s[3] * inv2 };
        *(floatx4*)(out + ((size_t)(b * SEQ + r0 + r)) * DIM + c4) = ov;
    }
}

extern "C" void kernel_launch(void* const* d_in, const int* in_sizes, int n_in,
                              void* d_out, int out_size, void* d_ws, size_t ws_size,
                              hipStream_t stream) {
    const float* q = (const float*)d_in[0];
    const float* k = (const float*)d_in[1];
    const float* v = (const float*)d_in[2];
    const int* mask = (const int*)d_in[3];   // bool delivered as int32 per harness

    float* out  = (float*)d_out;                       // [16,2048,64]
    float* attn = out + (size_t)NB * SEQ * DIM;        // [16,2048,2048]

    // workspace: qh | kh | vt (f16, 4 MB each) | bits (8 MB) = 20 MB total
    _Float16* qh = (_Float16*)d_ws;
    _Float16* kh = qh + (size_t)NB * SEQ * DIM;
    _Float16* vt = kh + (size_t)NB * SEQ * DIM;
    unsigned int* bits = (unsigned int*)(vt + (size_t)NB * SEQ * DIM);

    cvt_qk_kernel<<<(NB * SEQ * DIM) / 1024, 256, 0, stream>>>(q, k, qh, kh);
    cvt_vt_kernel<<<NB * (SEQ / 64), 256, 0, stream>>>(v, vt);
    mask_bits_kernel<<<(NB * SEQ) / 4, 256, 0, stream>>>(mask, bits);
    attn_kernel<<<NB * (SEQ / 16), 256, 0, stream>>>(qh, kh, vt, bits, out, attn);
}